// Round 1
// baseline (590.868 us; speedup 1.0000x reference)
//
#include <hip/hip_runtime.h>
#include <hip/hip_bf16.h>
#include <limits.h>

// Problem constants (from reference)
#define BB   4
#define NN   2048
#define CC   512
#define TSZ  9
#define TSTEP 6
#define TCUT 2
#define GRIDW 120
#define NCELL (GRIDW * GRIDW)
#define TILE_ELEMS (CC * TSZ * TSZ)      // 41472
#define OUT_PER_TILE (TILE_ELEMS + 1)    // 41473 (f_ns entry + tile)

// ---------------- Kernel 1: init cellmap + bbox ----------------
__global__ void init_kernel(int* __restrict__ bbox, int* __restrict__ cellmap) {
    int i = blockIdx.x * blockDim.x + threadIdx.x;
    if (i < 16) {
        // per batch: [ymin, ymax, xmin, xmax] -> init ymin/xmin to MAX, ymax/xmax to MIN
        bbox[i] = (i & 1) ? INT_MIN : INT_MAX;
    }
    for (int j = i; j < BB * NCELL; j += gridDim.x * blockDim.x)
        cellmap[j] = -1;
}

// ---------------- Kernel 2: scatter points, compute bbox ----------------
__global__ void scatter_kernel(const int* __restrict__ ys, const int* __restrict__ xs,
                               int* __restrict__ bbox, int* __restrict__ cellmap) {
    int i = blockIdx.x * blockDim.x + threadIdx.x;
    if (i >= BB * NN) return;
    int b = i / NN;
    int y = ys[i], x = xs[i];
    if (y < 0) return;   // reference filters ys > -1 (never triggers for this data)
    atomicMin(&bbox[b * 4 + 0], y);
    atomicMax(&bbox[b * 4 + 1], y);
    atomicMin(&bbox[b * 4 + 2], x);
    atomicMax(&bbox[b * 4 + 3], x);
    cellmap[b * NCELL + y * GRIDW + x] = i - b * NN;   // point index within batch
}

// ---------------- Kernel 3: select tiles + ordered compaction ----------------
// Single block, 512 threads (8 waves). Tiles per batch <= 21*21 = 441 < 512.
__global__ void select_kernel(const int* __restrict__ bbox, const int* __restrict__ cellmap,
                              int4* __restrict__ tileinfo, float* __restrict__ f_ns) {
    __shared__ int s_off;
    __shared__ int s_wave[8];
    const int tid = threadIdx.x;
    const int lane = tid & 63;
    const int wid = tid >> 6;
    if (tid == 0) s_off = 0;
    __syncthreads();

    for (int b = 0; b < BB; ++b) {
        int ymin = bbox[b * 4 + 0];
        int ymax = bbox[b * 4 + 1];
        int xmin = bbox[b * 4 + 2];
        int xmax = bbox[b * 4 + 3];
        int nH = (ymax - ymin + 1) / TSTEP + 1;   // (H - T_SZ)//T_STEP + 1
        int nW = (xmax - xmin + 1) / TSTEP + 1;
        int nT = nH * nW;

        for (int base = 0; base < nT; base += blockDim.x) {
            int t = base + tid;
            bool m = false;
            int gy0 = 0, gx0 = 0;
            if (t < nT) {
                int ti = t / nW, tj = t - ti * nW;
                gy0 = ymin + ti * TSTEP;
                gx0 = xmin + tj * TSTEP;
                // center 5x5: rows gy0+2..gy0+6, cols gx0+2..gx0+6
                for (int dy = TCUT; dy <= TSZ - 1 - TCUT && !m; ++dy) {
                    int gy = gy0 + dy;
                    if (gy >= GRIDW) break;
                    const int* row = cellmap + b * NCELL + gy * GRIDW;
                    for (int dx = TCUT; dx <= TSZ - 1 - TCUT; ++dx) {
                        int gx = gx0 + dx;
                        if (gx >= GRIDW) break;
                        if (row[gx] >= 0) { m = true; break; }
                    }
                }
            }
            unsigned long long bal = __ballot(m);
            int lpre = __popcll(bal & ((lane == 0) ? 0ull : ((1ull << lane) - 1ull)));
            if (lane == 0) s_wave[wid] = (int)__popcll(bal);
            __syncthreads();
            if (tid == 0) {
                int acc = s_off;
                for (int w = 0; w < 8; ++w) { int v = s_wave[w]; s_wave[w] = acc; acc += v; }
                s_off = acc;
            }
            __syncthreads();
            if (m) {
                int idx = s_wave[wid] + lpre;
                tileinfo[idx] = make_int4(b, gy0, gx0, 0);
                f_ns[idx] = (float)b;
            }
            __syncthreads();
        }
    }
}

// ---------------- Kernel 4: fill output tiles ----------------
__global__ void fill_kernel(const float* __restrict__ feats, const int* __restrict__ cellmap,
                            const int4* __restrict__ tileinfo, float* __restrict__ out_tiles,
                            int total) {
    int e = blockIdx.x * blockDim.x + threadIdx.x;
    if (e >= total) return;
    int k = e / TILE_ELEMS;
    int rem = e - k * TILE_ELEMS;
    int c = rem / (TSZ * TSZ);
    int cell = rem - c * (TSZ * TSZ);
    int4 ti = tileinfo[k];
    int gy = ti.y + cell / TSZ;
    int gx = ti.z + cell - (cell / TSZ) * TSZ;
    float v = 0.0f;
    if (gy < GRIDW && gx < GRIDW) {
        int n = cellmap[ti.x * NCELL + gy * GRIDW + gx];
        if (n >= 0) v = feats[((long long)ti.x * NN + n) * CC + c];
    }
    out_tiles[e] = v;
}

extern "C" void kernel_launch(void* const* d_in, const int* in_sizes, int n_in,
                              void* d_out, int out_size, void* d_ws, size_t ws_size,
                              hipStream_t stream) {
    const float* feats = (const float*)d_in[0];
    const int* ys = (const int*)d_in[1];
    const int* xs = (const int*)d_in[2];
    float* out = (float*)d_out;

    char* ws = (char*)d_ws;
    int* bbox = (int*)ws;                          // 16 ints
    int* cellmap = (int*)(ws + 256);               // 4*14400 ints = 230400 B
    int4* tileinfo = (int4*)(ws + 256 + BB * NCELL * 4);  // offset 230656 (16-aligned)

    const int K = out_size / OUT_PER_TILE;         // number of selected tiles
    float* f_ns = out;                              // first K floats
    float* out_tiles = out + K;                     // K * 41472 floats

    {
        int n = BB * NCELL;
        init_kernel<<<(n + 255) / 256, 256, 0, stream>>>(bbox, cellmap);
    }
    {
        int n = BB * NN;
        scatter_kernel<<<(n + 255) / 256, 256, 0, stream>>>(ys, xs, bbox, cellmap);
    }
    select_kernel<<<1, 512, 0, stream>>>(bbox, cellmap, tileinfo, f_ns);
    {
        int total = K * TILE_ELEMS;
        fill_kernel<<<(total + 255) / 256, 256, 0, stream>>>(feats, cellmap, tileinfo, out_tiles, total);
    }
}

// Round 2
// 115.644 us; speedup vs baseline: 5.1094x; 5.1094x over previous
//
#include <hip/hip_runtime.h>
#include <hip/hip_bf16.h>
#include <limits.h>

// Problem constants (from reference)
#define BB   4
#define NN   2048
#define CC   512
#define TSZ  9
#define TSTEP 6
#define TCUT 2
#define GRIDW 120
#define NCELL (GRIDW * GRIDW)
#define TILE_ELEMS (CC * TSZ * TSZ)      // 41472
#define OUT_PER_TILE (TILE_ELEMS + 1)    // 41473 (f_ns entry + tile)

// ---------------- Kernel 1: init cellmap ----------------
__global__ void init_kernel(int* __restrict__ cellmap) {
    int i = blockIdx.x * blockDim.x + threadIdx.x;
    if (i < BB * NCELL) cellmap[i] = -1;
}

// ---------------- Kernel 2: scatter points (no atomics) ----------------
__global__ void scatter_kernel(const int* __restrict__ ys, const int* __restrict__ xs,
                               int* __restrict__ cellmap) {
    int i = blockIdx.x * blockDim.x + threadIdx.x;
    if (i >= BB * NN) return;
    int b = i >> 11;                      // i / NN
    int y = ys[i], x = xs[i];
    if (y < 0) return;                    // reference filters ys > -1
    cellmap[b * NCELL + y * GRIDW + x] = i - b * NN;   // point index within batch
}

// ---------------- Kernel 3: bbox reduce + select tiles + ordered compaction ----------------
// Single block, 512 threads (8 waves). Tiles per batch <= 21*21 = 441 < 512.
__global__ __launch_bounds__(512) void select_kernel(
        const int* __restrict__ ys, const int* __restrict__ xs,
        const int* __restrict__ cellmap,
        int4* __restrict__ tileinfo, float* __restrict__ f_ns) {
    __shared__ int s_off;
    __shared__ int s_wave[8];
    __shared__ int s_red[8][4];
    __shared__ int s_bbox[4];
    const int tid = threadIdx.x;
    const int lane = tid & 63;
    const int wid = tid >> 6;
    if (tid == 0) s_off = 0;

    for (int b = 0; b < BB; ++b) {
        // ---- bbox reduction over this batch's 2048 points ----
        int ymin = INT_MAX, ymax = INT_MIN, xmin = INT_MAX, xmax = INT_MIN;
        for (int j = tid; j < NN; j += 512) {
            int y = ys[b * NN + j], x = xs[b * NN + j];
            if (y > -1) {
                ymin = min(ymin, y); ymax = max(ymax, y);
                xmin = min(xmin, x); xmax = max(xmax, x);
            }
        }
        #pragma unroll
        for (int off = 32; off; off >>= 1) {
            ymin = min(ymin, __shfl_xor(ymin, off));
            ymax = max(ymax, __shfl_xor(ymax, off));
            xmin = min(xmin, __shfl_xor(xmin, off));
            xmax = max(xmax, __shfl_xor(xmax, off));
        }
        if (lane == 0) {
            s_red[wid][0] = ymin; s_red[wid][1] = ymax;
            s_red[wid][2] = xmin; s_red[wid][3] = xmax;
        }
        __syncthreads();
        if (tid == 0) {
            int a = INT_MAX, bmx = INT_MIN, c = INT_MAX, d = INT_MIN;
            for (int w = 0; w < 8; ++w) {
                a = min(a, s_red[w][0]); bmx = max(bmx, s_red[w][1]);
                c = min(c, s_red[w][2]); d = max(d, s_red[w][3]);
            }
            s_bbox[0] = a; s_bbox[1] = bmx; s_bbox[2] = c; s_bbox[3] = d;
        }
        __syncthreads();
        ymin = s_bbox[0]; ymax = s_bbox[1]; xmin = s_bbox[2]; xmax = s_bbox[3];

        int nH = (ymax - ymin + 1) / TSTEP + 1;   // (H - T_SZ)//T_STEP + 1
        int nW = (xmax - xmin + 1) / TSTEP + 1;
        int nT = nH * nW;

        for (int base = 0; base < nT; base += 512) {
            int t = base + tid;
            bool m = false;
            int gy0 = 0, gx0 = 0;
            if (t < nT) {
                int ti = t / nW, tj = t - ti * nW;
                gy0 = ymin + ti * TSTEP;
                gx0 = xmin + tj * TSTEP;
                // center 5x5: rows gy0+2..gy0+6, cols gx0+2..gx0+6
                for (int dy = TCUT; dy <= TSZ - 1 - TCUT && !m; ++dy) {
                    int gy = gy0 + dy;
                    if (gy >= GRIDW) break;
                    const int* row = cellmap + b * NCELL + gy * GRIDW;
                    for (int dx = TCUT; dx <= TSZ - 1 - TCUT; ++dx) {
                        int gx = gx0 + dx;
                        if (gx >= GRIDW) break;
                        if (row[gx] >= 0) { m = true; break; }
                    }
                }
            }
            unsigned long long bal = __ballot(m);
            int lpre = __popcll(bal & ((lane == 0) ? 0ull : ((1ull << lane) - 1ull)));
            if (lane == 0) s_wave[wid] = (int)__popcll(bal);
            __syncthreads();
            if (tid == 0) {
                int acc = s_off;
                for (int w = 0; w < 8; ++w) { int v = s_wave[w]; s_wave[w] = acc; acc += v; }
                s_off = acc;
            }
            __syncthreads();
            if (m) {
                int idx = s_wave[wid] + lpre;
                tileinfo[idx] = make_int4(b, gy0, gx0, 0);
                f_ns[idx] = (float)b;
            }
            __syncthreads();
        }
    }
}

// ---------------- Kernel 4: fill output tiles ----------------
// One block per tile. 81 cellmap lookups cached in LDS; float4 coalesced writes.
__global__ __launch_bounds__(256) void fill_kernel(
        const float* __restrict__ feats, const int* __restrict__ cellmap,
        const int4* __restrict__ tileinfo, float* __restrict__ out_tiles) {
    __shared__ int s_n[81];
    const int k = blockIdx.x;
    const int tid = threadIdx.x;
    int4 ti = tileinfo[k];
    if (tid < 81) {
        int gy = ti.y + tid / 9;
        int gx = ti.z + tid - (tid / 9) * 9;
        int n = -1;
        if (gy < GRIDW && gx < GRIDW) n = cellmap[ti.x * NCELL + gy * GRIDW + gx];
        s_n[tid] = n;
    }
    __syncthreads();
    const float* __restrict__ fb = feats + (size_t)ti.x * (NN * CC);
    float* __restrict__ outk = out_tiles + (size_t)k * TILE_ELEMS;

    // 41472 = 40 * 1024 + 512 : 40 float4 iterations + one float2 tail
    #pragma unroll 2
    for (int it = 0; it < 40; ++it) {
        int idx = it * 1024 + tid * 4;
        int c = idx / 81;
        int cell = idx - c * 81;
        float v[4];
        #pragma unroll
        for (int j = 0; j < 4; ++j) {
            int cc = c, ce = cell + j;
            if (ce >= 81) { ce -= 81; cc += 1; }
            int n = s_n[ce];
            v[j] = (n >= 0) ? fb[n * CC + cc] : 0.0f;
        }
        *(float4*)(outk + idx) = make_float4(v[0], v[1], v[2], v[3]);
    }
    {
        int idx = 40960 + tid * 2;
        int c = idx / 81;
        int cell = idx - c * 81;
        float v[2];
        #pragma unroll
        for (int j = 0; j < 2; ++j) {
            int cc = c, ce = cell + j;
            if (ce >= 81) { ce -= 81; cc += 1; }
            int n = s_n[ce];
            v[j] = (n >= 0) ? fb[n * CC + cc] : 0.0f;
        }
        *(float2*)(outk + idx) = make_float2(v[0], v[1]);
    }
}

extern "C" void kernel_launch(void* const* d_in, const int* in_sizes, int n_in,
                              void* d_out, int out_size, void* d_ws, size_t ws_size,
                              hipStream_t stream) {
    const float* feats = (const float*)d_in[0];
    const int* ys = (const int*)d_in[1];
    const int* xs = (const int*)d_in[2];
    float* out = (float*)d_out;

    char* ws = (char*)d_ws;
    int* cellmap = (int*)ws;                                  // 4*14400 ints = 230400 B
    int4* tileinfo = (int4*)(ws + BB * NCELL * 4 + 256);      // 16-aligned

    const int K = out_size / OUT_PER_TILE;         // number of selected tiles
    float* f_ns = out;                              // first K floats
    float* out_tiles = out + K;                     // K * 41472 floats

    {
        int n = BB * NCELL;
        init_kernel<<<(n + 255) / 256, 256, 0, stream>>>(cellmap);
    }
    {
        int n = BB * NN;
        scatter_kernel<<<(n + 255) / 256, 256, 0, stream>>>(ys, xs, cellmap);
    }
    select_kernel<<<1, 512, 0, stream>>>(ys, xs, cellmap, tileinfo, f_ns);
    fill_kernel<<<K, 256, 0, stream>>>(feats, cellmap, tileinfo, out_tiles);
}